// Round 8
// baseline (436.172 us; speedup 1.0000x reference)
//
#include <hip/hip_runtime.h>
#include <hip/hip_bf16.h>

#define NN 200000
#define ND 128
#define GD 128
#define HID 512
#define NG 1024

typedef __bf16 bf16x8 __attribute__((ext_vector_type(8)));
typedef unsigned short u16x8 __attribute__((ext_vector_type(8)));
typedef float f32x16 __attribute__((ext_vector_type(16)));
typedef unsigned u32x4 __attribute__((ext_vector_type(4)));

// packed-weight bases in bf16 elements inside d_ws
#define PK_WI1 0u
#define PK_WI2 131072u
#define PK_WJ1 196608u
#define PK_WJ2 262144u

__device__ __forceinline__ unsigned short f2bf(float x){
  unsigned u = __builtin_bit_cast(unsigned, x);
  u += 0x7FFFu + ((u >> 16) & 1u);          // RNE
  return (unsigned short)(u >> 16);
}
__device__ __forceinline__ float bf2f(unsigned short h){
  return __builtin_bit_cast(float, ((unsigned)h) << 16);
}
__device__ __forceinline__ unsigned pkbf2(float a, float b){
  unsigned lo = __builtin_bit_cast(unsigned short, __float2bfloat16(a));
  unsigned hi = __builtin_bit_cast(unsigned short, __float2bfloat16(b));
  return lo | (hi << 16);
}
__device__ __forceinline__ f32x16 mfma_bf16(u16x8 a, u16x8 b, f32x16 c){
  return __builtin_amdgcn_mfma_f32_32x32x16_bf16(
      __builtin_bit_cast(bf16x8, a), __builtin_bit_cast(bf16x8, b), c, 0, 0, 0);
}
// sigma: swap bits 2 and 3 (layer-1 column permutation so the swapped-MFMA
// D-layout lands in B-frag element order for the register-fed layer 2)
__device__ __forceinline__ int sigswap(int l){
  return (l & 0x13) | ((l & 4) << 1) | ((l & 8) >> 1);
}

// ---- pack fp32 weights [K][N] -> bf16 B-fragment order for 32x32x16 ----
// frag(kt,nt): lane holds B[kt*16 + (lane>>5)*8 + j][nt*32 + col(lane&31)]
// col = sigswap(l31) for LAYER-1 weights (Wi1/Wj1), identity for layer-2.
// Derivation: D of mfma(W1frag, Xfrag) has lane(l31,q) reg r at
// m=(r&3)+8*(r>>2)+4q; sigma(m) = 16*(r>>3)+8q+(r&7), so packed reg pairs
// (2g,2g+1) are consecutive hid and words g=0..3 / 4..7 form exactly the
// B-frag (k=q*8+j) element order of the two layer-2 k-tiles. (verified alg.)
// Also zeroes the output accumulator (atomics target) — replaces memset.
__global__ void pack_w(const float* __restrict__ Wi1, const float* __restrict__ Wi2,
                       const float* __restrict__ Wj1, const float* __restrict__ Wj2,
                       unsigned short* __restrict__ pk, float* __restrict__ out){
  int g = blockIdx.x * 256 + threadIdx.x;   // 40960 groups of 8 elems
  if (g < 32768) ((float4*)out)[g] = make_float4(0.f, 0.f, 0.f, 0.f); // 131072 floats
  const float* W; int N; unsigned base; int f; int perm;
  if (g < 16384)      { W = Wi1; N = 512; base = PK_WI1; f = g;         perm = 1; }
  else if (g < 24576) { W = Wi2; N = 128; base = PK_WI2; f = g - 16384; perm = 0; }
  else if (g < 32768) { W = Wj1; N = 512; base = PK_WJ1; f = g - 24576; perm = 1; }
  else                { W = Wj2; N = 128; base = PK_WJ2; f = g - 32768; perm = 0; }
  int lane = f & 63;
  int t = f >> 6;
  int ntiles = N >> 5;
  int nt = t % ntiles, kt = t / ntiles;
  int k0 = kt * 16 + (lane >> 5) * 8;
  int l31 = lane & 31;
  int n  = nt * 32 + (perm ? sigswap(l31) : l31);
  u16x8 v;
  #pragma unroll
  for (int j = 0; j < 8; ++j) v[j] = f2bf(W[(size_t)(k0 + j) * N + n]);
  *(u16x8*)(pk + base + (size_t)f * 8) = v;
}

// write/accumulate one nt2-tile (both node tiles) into red[gd][node(66)]
template<bool WRITE>
__device__ __forceinline__ void red_tile(float* red, int ntb, int q, int l31,
                                         const f32x16& m0, const f32x16& m1){
  #pragma unroll
  for (int reg = 0; reg < 16; ++reg){
    int idx = ntb + ((reg & 3) + 8 * (reg >> 2) + 4 * q) * 66 + l31;
    if (WRITE){ red[idx] = m0[reg]; red[idx + 32] = m1[reg]; }
    else      { red[idx] += m0[reg]; red[idx + 32] += m1[reg]; }
  }
}

// ---- one MLP phase, fully register-resident between staging and reduce ----
// wave wv owns hid slab wv*32 (+c*128 per round). Per round:
//   L1: t = mfma(W1frag, Xfrag) -> (X W1)^T tile (hid in regs via sigma)
//   pack: bias+ReLU+pkbf2 -> 8 words/tile = 2 layer-2 B-frags per node tile
//   L2: racc[nt2][mt] += mfma(W2frag-as-A, pbfrag)  (partial over this slab)
// NO barriers in rounds. After 4 rounds: 4-step barriered reduce into red.
template<int NKT>
__device__ void mlp_phase(const unsigned short* __restrict__ pk,
                          const float* __restrict__ b1,
                          const unsigned short* Xs, float* red,
                          int lane, int l31, int q, int wv, int aB0, int aB1,
                          unsigned w1b, unsigned w2b)
{
  f32x16 racc[4][2];
  #pragma unroll
  for (int a = 0; a < 4; ++a)
    #pragma unroll
    for (int b = 0; b < 2; ++b)
      #pragma unroll
      for (int i = 0; i < 16; ++i) racc[a][b][i] = 0.f;

  #pragma unroll
  for (int c = 0; c < 4; ++c){
    // layer-1 bias, permuted layout: reg r (lane q) is hid 16*(r>>3)+8q+(r&7)
    const float* bc = b1 + c * 128 + wv * 32;
    float4 f0 = *(const float4*)(bc + 8 * q);
    float4 f1 = *(const float4*)(bc + 8 * q + 4);
    float4 f2 = *(const float4*)(bc + 16 + 8 * q);
    float4 f3 = *(const float4*)(bc + 16 + 8 * q + 4);
    f32x16 t0, t1;
    t0[0]=f0.x; t0[1]=f0.y; t0[2]=f0.z; t0[3]=f0.w;
    t0[4]=f1.x; t0[5]=f1.y; t0[6]=f1.z; t0[7]=f1.w;
    t0[8]=f2.x; t0[9]=f2.y; t0[10]=f2.z; t0[11]=f2.w;
    t0[12]=f3.x; t0[13]=f3.y; t0[14]=f3.z; t0[15]=f3.w;
    #pragma unroll
    for (int i = 0; i < 16; ++i) t1[i] = t0[i];

    __builtin_amdgcn_s_setprio(1);
    #pragma unroll
    for (int ktg = 0; ktg < NKT; ++ktg){
      u16x8 fw = *(const u16x8*)(pk + w1b +
                 (unsigned)(((ktg * 16 + c * 4 + wv) * 64 + lane) * 8));
      u16x8 x0 = *(const u16x8*)&Xs[aB0 + ktg * 16];
      u16x8 x1 = *(const u16x8*)&Xs[aB1 + ktg * 16];
      t0 = mfma_bf16(fw, x0, t0);          // (X W1)^T : hid in regs, node in lanes
      t1 = mfma_bf16(fw, x1, t1);
    }
    __builtin_amdgcn_s_setprio(0);

    // ReLU + pack: words g = consecutive-hid pairs (sigma guarantees this)
    unsigned uA[8], uB[8];
    #pragma unroll
    for (int g = 0; g < 8; ++g){
      uA[g] = pkbf2(fmaxf(t0[2*g], 0.f), fmaxf(t0[2*g+1], 0.f));
      uB[g] = pkbf2(fmaxf(t1[2*g], 0.f), fmaxf(t1[2*g+1], 0.f));
    }
    u16x8 p00 = __builtin_bit_cast(u16x8, (u32x4){uA[0],uA[1],uA[2],uA[3]}); // mt0 kk0
    u16x8 p01 = __builtin_bit_cast(u16x8, (u32x4){uA[4],uA[5],uA[6],uA[7]}); // mt0 kk1
    u16x8 p10 = __builtin_bit_cast(u16x8, (u32x4){uB[0],uB[1],uB[2],uB[3]}); // mt1 kk0
    u16x8 p11 = __builtin_bit_cast(u16x8, (u32x4){uB[4],uB[5],uB[6],uB[7]}); // mt1 kk1

    // layer 2: W2frag used as A-operand reads as W2^T (verified duality)
    __builtin_amdgcn_s_setprio(1);
    #pragma unroll
    for (int kk = 0; kk < 2; ++kk){
      #pragma unroll
      for (int nt2 = 0; nt2 < 4; ++nt2){
        u16x8 w2f = *(const u16x8*)(pk + w2b +
                    (unsigned)((((c * 8 + wv * 2 + kk) * 4 + nt2) * 64 + lane) * 8));
        racc[nt2][0] = mfma_bf16(w2f, kk ? p01 : p00, racc[nt2][0]);
        racc[nt2][1] = mfma_bf16(w2f, kk ? p11 : p10, racc[nt2][1]);
      }
    }
    __builtin_amdgcn_s_setprio(0);
  }

  // ---- 4-step cross-wave reduction: step s, wave wv handles nt2=(wv+s)&3 ----
  __syncthreads();   // red free (previous consumers done)
  #pragma unroll
  for (int s = 0; s < 4; ++s){
    int sel = (wv + s) & 3;
    if (s == 0){
      switch (sel){
        case 0: red_tile<true >(red, 0*32*66, q, l31, racc[0][0], racc[0][1]); break;
        case 1: red_tile<true >(red, 1*32*66, q, l31, racc[1][0], racc[1][1]); break;
        case 2: red_tile<true >(red, 2*32*66, q, l31, racc[2][0], racc[2][1]); break;
        default:red_tile<true >(red, 3*32*66, q, l31, racc[3][0], racc[3][1]); break;
      }
    } else {
      switch (sel){
        case 0: red_tile<false>(red, 0*32*66, q, l31, racc[0][0], racc[0][1]); break;
        case 1: red_tile<false>(red, 1*32*66, q, l31, racc[1][0], racc[1][1]); break;
        case 2: red_tile<false>(red, 2*32*66, q, l31, racc[2][0], racc[2][1]); break;
        default:red_tile<false>(red, 3*32*66, q, l31, racc[3][0], racc[3][1]); break;
      }
    }
    __syncthreads();
  }
}

// ---- main fused kernel: 4 waves per block, 64 nodes per block ----
__global__ __launch_bounds__(256, 2)
void readout_main(const float* __restrict__ hT, const float* __restrict__ h0,
                  const int* __restrict__ gi,
                  const float* __restrict__ bi1, const float* __restrict__ bi2,
                  const float* __restrict__ bj1, const float* __restrict__ bj2,
                  const unsigned short* __restrict__ pk,
                  float* __restrict__ out){
  __shared__ __align__(16) unsigned short Xs[64 * 264]; // bf16 [64][256+8]
  __shared__ __align__(16) float red[128 * 66];         // f32 [gd=128][node 64+2]
  __shared__ int gids[64];

  const int tid  = threadIdx.x;
  const int lane = tid & 63;
  const int wv   = tid >> 6;                // 0..3 = hid-quarter
  const int l31  = lane & 31;
  const int q    = lane >> 5;
  const int m0   = blockIdx.x * 64;         // 200000 = 3125*64 exact

  const int col  = wv * 32 + l31;           // this lane's output gd column
  const float bb2i = bi2[col];
  const float bb2j = bj2[col];

  // gids probe: issue loads up front (latency hides under staging)
  int gv32 = 0, gv64 = 0, glast = 0;
  if (tid < 64){
    glast = gi[NN - 1];
    gv32  = gi[m0 + tid];
    gv64  = gi[2 * (m0 + tid)];
  }

  // ---- stage X = [h_T | h_0] as bf16 (all 256 threads, 8 iters) ----
  #pragma unroll
  for (int it = 0; it < 8; ++it){
    int flat = it * 256 + tid;              // 0..2047
    int r  = flat >> 5;                     // 0..63
    int c4 = flat & 31;
    const float4 vT = ((const float4*)(hT + (size_t)(m0 + r) * ND))[c4];
    const float4 v0 = ((const float4*)(h0 + (size_t)(m0 + r) * ND))[c4];
    uint2 pT, p0;
    pT.x = pkbf2(vT.x, vT.y);
    pT.y = pkbf2(vT.z, vT.w);
    p0.x = pkbf2(v0.x, v0.y);
    p0.y = pkbf2(v0.z, v0.w);
    *(uint2*)&Xs[r * 264 + c4 * 4]       = pT;
    *(uint2*)&Xs[r * 264 + 128 + c4 * 4] = p0;
  }
  if (tid < 64){
    // dtype probe: sorted indices end at 1023 -> int32 layout; int64 high word -> 0
    gids[tid] = (glast == 0) ? gv64 : gv32;
  }
  __syncthreads();

  const int aB0 = l31 * 264 + q * 8;        // X-frag node tile 0 (nodes 0..31)
  const int aB1 = (32 + l31) * 264 + q * 8; // X-frag node tile 1 (nodes 32..63)

  // ================= phase i: gate presums -> red =================
  mlp_phase<16>(pk, bi1, Xs, red, lane, l31, q, wv, aB0, aB1, PK_WI1, PK_WI2);

  // gate = sigmoid(red + bi2), read in column orientation, packed bf16
  unsigned gpk[16];
  {
    const float* rp = red + col * 66 + q * 32;
    #pragma unroll
    for (int i2 = 0; i2 < 16; ++i2){
      float x0 = rp[2 * i2]     + bb2i;
      float x1 = rp[2 * i2 + 1] + bb2i;
      float s0 = 1.f / (1.f + __expf(-x0));
      float s1 = 1.f / (1.f + __expf(-x1));
      gpk[i2] = pkbf2(s0, s1);
    }
  }
  // phase j's reduce-start barrier orders these reads before red is rewritten

  // ================= phase j: j presums -> red =================
  mlp_phase<8>(pk, bj1, Xs, red, lane, l31, q, wv, aB0, aB1, PK_WJ1, PK_WJ2);

  // ======== epilogue: R_v = gate * (red_j + bj2); sorted-run atomics ========
  // lane owns col; visits its 32 consecutive nodes q*32.. in ascending order.
  {
    const float* rp = red + col * 66 + q * 32;
    float acc = 0.f; int cg = -1;
    #pragma unroll
    for (int i = 0; i < 32; ++i){
      float jv = rp[i] + bb2j;
      unsigned gw = gpk[i >> 1];
      float gv = bf2f((unsigned short)((i & 1) ? (gw >> 16) : (gw & 0xFFFFu)));
      float rv = gv * jv;
      int g = gids[q * 32 + i];
      if (g != cg){
        if (cg >= 0) atomicAdd(out + (unsigned)cg * GD + col, acc);
        acc = 0.f; cg = g;
      }
      acc += rv;
    }
    atomicAdd(out + (unsigned)cg * GD + col, acc);
  }
}

extern "C" void kernel_launch(void* const* d_in, const int* in_sizes, int n_in,
                              void* d_out, int out_size, void* d_ws, size_t ws_size,
                              hipStream_t stream){
  const float* hT  = (const float*)d_in[0];
  const float* h0  = (const float*)d_in[1];
  const int*   gi  = (const int*)d_in[2];
  const float* Wi1 = (const float*)d_in[3];
  const float* bi1 = (const float*)d_in[4];
  const float* Wi2 = (const float*)d_in[5];
  const float* bi2 = (const float*)d_in[6];
  const float* Wj1 = (const float*)d_in[7];
  const float* bj1 = (const float*)d_in[8];
  const float* Wj2 = (const float*)d_in[9];
  const float* bj2 = (const float*)d_in[10];
  float* out = (float*)d_out;
  unsigned short* pk = (unsigned short*)d_ws; // needs 655360 B

  pack_w<<<160, 256, 0, stream>>>(Wi1, Wi2, Wj1, Wj2, pk, out);
  readout_main<<<NN / 64, 256, 0, stream>>>(hT, h0, gi, bi1, bi2, bj1, bj2, pk, out);
}